// Round 3
// baseline (1370.568 us; speedup 1.0000x reference)
//
#include <hip/hip_runtime.h>
#include <hip/hip_bf16.h>
#include <cstdint>
#include <cstddef>

// Problem dims
#define BATCH 8192
#define DIN   2048
#define HID   2048
#define KDIM  4096   // D + H
#define NDIM  8192   // 4*H
#define MDIM  8192   // batch
#define BH    16777216  // BATCH*HID
#define NT    64     // K tiles of 64

typedef unsigned short u16;
typedef __bf16 bf16x8 __attribute__((ext_vector_type(8)));
typedef float  f32x4  __attribute__((ext_vector_type(4)));
typedef float  f32x8  __attribute__((ext_vector_type(8)));

// ---------- helpers ----------
__device__ __forceinline__ u16 f2bf(float f) {
    union { float f; unsigned u; } a; a.f = f;
    unsigned u = a.u;
    unsigned r = u + 0x7FFFu + ((u >> 16) & 1u);   // RNE
    return (u16)(r >> 16);
}
__device__ __forceinline__ float lo16(unsigned v) {
    union { unsigned u; float f; } a; a.u = v << 16; return a.f;
}
__device__ __forceinline__ float hi16(unsigned v) {
    union { unsigned u; float f; } a; a.u = v & 0xFFFF0000u; return a.f;
}
__device__ __forceinline__ void unpack8(uint4 p, float* f) {
    f[0] = lo16(p.x); f[1] = hi16(p.x);
    f[2] = lo16(p.y); f[3] = hi16(p.y);
    f[4] = lo16(p.z); f[5] = hi16(p.z);
    f[6] = lo16(p.w); f[7] = hi16(p.w);
}
__device__ __forceinline__ float sigm(float x) {
    return 1.0f / (1.0f + __expf(-x));
}
__device__ __forceinline__ float tanh_fast(float x) {
    return 1.0f - 2.0f / (__expf(2.0f * x) + 1.0f);
}
// fp32x8 -> bf16x8 (RNE, v_cvt_pk_bf16_f32) -> 16B LDS store
__device__ __forceinline__ void cvt_write(void* dst, float4 a, float4 b) {
    union { float4 q[2]; f32x8 v; } u; u.q[0] = a; u.q[1] = b;
    bf16x8 o = __builtin_convertvector(u.v, bf16x8);
    *(bf16x8*)dst = o;
}

// ---------- fully fused: cast + GEMM + LSTM epilogue ----------
// C[m,n] = sum_k A[m,k]*W[n,k] with A=[x|h0] (fp32, cast in staging),
// W rows = gate g of [W_i|W_h], n = {g*2048 + hb0 + [0,64)}, g=0..3.
// Then i,f,g,o -> (h_t, c_t) written directly.
//
// 256(m) x 256(n) tile, BK=64, 8 waves (2m x 4n), 512 threads.
// 4-phase schedule (round-2 verified structure: same reads/MFMA/barriers),
// reg-staged fp32->bf16 conversion replaces global_load_lds:
//   sets: A02 (issue p0 -> write p2), B01 (p1 -> p3), B23 (p2 -> p3),
//         A13 (p3 -> next tile's p0).  Peak staging regs ~32.
// LDS write swizzle: granule g' = g ^ (row&7) -- identical mapping to the
// old pre-swizzled-source global_load_lds, so the ds_read side (coff) is
// unchanged.  Every ds_write is followed in-phase by ds_reads whose MFMA
// lgkm-waits retire it (in-order LDS) before the next barrier.
__global__ __launch_bounds__(512, 2) void gemm_lstm_kernel(
    const float* __restrict__ x,      // [8192, 2048]
    const float* __restrict__ h0,     // [8192, 2048]
    const float* __restrict__ c0,
    const float* __restrict__ Wii, const float* __restrict__ Wif,
    const float* __restrict__ Wig, const float* __restrict__ Wio,
    const float* __restrict__ Whi, const float* __restrict__ Whf,
    const float* __restrict__ Whg, const float* __restrict__ Who,
    const float* __restrict__ bii, const float* __restrict__ bhi,
    const float* __restrict__ bif, const float* __restrict__ bhf,
    const float* __restrict__ big, const float* __restrict__ bhg,
    const float* __restrict__ bio, const float* __restrict__ bho,
    float* __restrict__ out)
{
    __shared__ u16 SM[65536];      // 128 KiB: A dbuf [0,64K)B, B dbuf [64K,128K)B

    const int tid  = threadIdx.x;
    const int lane = tid & 63;
    const int wave = tid >> 6;
    const int wm   = wave >> 2;       // 0..1  (128 m-rows each)
    const int wn   = wave & 3;        // 0..3  == gate id (64 cols each)
    const int quad = lane >> 4;
    const int l16  = lane & 15;

    // XCD-aware bijective block swizzle (1024 blocks, 1024 % 8 == 0)
    const int wg = ((blockIdx.x & 7) << 7) + (blockIdx.x >> 3);
    const size_t m0  = (size_t)(wg >> 5) * 256;   // batch-row base
    const size_t hb0 = (size_t)(wg & 31) * 64;    // hidden-col base

    // ---- staging addressing ----
    const int rr  = tid >> 3;                      // LDS row within 64-row issue
    const int g8  = (tid & 7) * 8;                 // linear f32 granule offset
    const int gsw = ((tid & 7) ^ (rr & 7)) * 16;   // swizzled dest byte offset
    const size_t aoff = (m0 + rr) * 2048 + g8;     // + J*64*2048 per A issue
    const size_t boff = (hb0 + rr) * 2048 + g8;    // gate row (same for all J)
    char* smB = (char*)SM;

    float4 stA[4], stB0[4], stB1[4];

#define BP0(u2) (((u2) < 32) ? Wii : Whi)
#define BP1(u2) (((u2) < 32) ? Wif : Whf)
#define BP2(u2) (((u2) < 32) ? Wig : Whg)
#define BP3(u2) (((u2) < 32) ? Wio : Who)

#define ISS_A(dst, JA, JB, u2) { \
    const float* pa_ = (((u2) < 32) ? x : h0) + (((u2) & 31) << 6); \
    dst[0] = *(const float4*)(pa_ + aoff + (JA) * 131072); \
    dst[1] = *(const float4*)(pa_ + aoff + (JA) * 131072 + 4); \
    dst[2] = *(const float4*)(pa_ + aoff + (JB) * 131072); \
    dst[3] = *(const float4*)(pa_ + aoff + (JB) * 131072 + 4); }
#define ISS_B01(u2) { \
    const float* pb0_ = BP0(u2) + (((u2) & 31) << 6); \
    const float* pb1_ = BP1(u2) + (((u2) & 31) << 6); \
    stB0[0] = *(const float4*)(pb0_ + boff); \
    stB0[1] = *(const float4*)(pb0_ + boff + 4); \
    stB0[2] = *(const float4*)(pb1_ + boff); \
    stB0[3] = *(const float4*)(pb1_ + boff + 4); }
#define ISS_B23(u2) { \
    const float* pb2_ = BP2(u2) + (((u2) & 31) << 6); \
    const float* pb3_ = BP3(u2) + (((u2) & 31) << 6); \
    stB1[0] = *(const float4*)(pb2_ + boff); \
    stB1[1] = *(const float4*)(pb2_ + boff + 4); \
    stB1[2] = *(const float4*)(pb3_ + boff); \
    stB1[3] = *(const float4*)(pb3_ + boff + 4); }

// dest byte: A region = BUF*32768, B region = 65536 + BUF*32768
#define WRTJ(baseB, J_, q0, q1) \
    cvt_write(smB + (baseB) + (J_) * 8192 + rr * 128 + gsw, q0, q1)
#define WRT_A02(BUF) { WRTJ((BUF)*32768, 0, stA[0], stA[1]);  WRTJ((BUF)*32768, 2, stA[2], stA[3]); }
#define WRT_A13(BUF) { WRTJ((BUF)*32768, 1, stA[0], stA[1]);  WRTJ((BUF)*32768, 3, stA[2], stA[3]); }
#define WRT_B01(BUF) { WRTJ(65536+(BUF)*32768, 0, stB0[0], stB0[1]); WRTJ(65536+(BUF)*32768, 1, stB0[2], stB0[3]); }
#define WRT_B23(BUF) { WRTJ(65536+(BUF)*32768, 2, stB1[0], stB1[1]); WRTJ(65536+(BUF)*32768, 3, stB1[2], stB1[3]); }

    f32x4 acc[8][4];
    #pragma unroll
    for (int i = 0; i < 8; ++i)
        #pragma unroll
        for (int j = 0; j < 4; ++j)
            acc[i][j] = (f32x4){0.f, 0.f, 0.f, 0.f};

    // ---- fragment read addressing (u16 units; identical to round 2) ----
    const int a_base = (wm * 128 + l16) * 64;
    const int b_base = (wn * 64 + l16) * 64;
    int coff[2];
    coff[0] = (quad * 8) ^ ((l16 & 7) * 8);
    coff[1] = coff[0] ^ 32;

    bf16x8 af[4][2], bfr[2][2];

#define LDA(MH) { _Pragma("unroll") for (int i = 0; i < 4; ++i) {                        \
                    _Pragma("unroll") for (int k = 0; k < 2; ++k)                        \
                      af[i][k] = *(const bf16x8*)&SM[cur * 16384 + a_base + ((MH)*4 + i) * 1024 + coff[k]]; } }
#define LDB(NH) { _Pragma("unroll") for (int j = 0; j < 2; ++j) {                        \
                    _Pragma("unroll") for (int k = 0; k < 2; ++k)                        \
                      bfr[j][k] = *(const bf16x8*)&SM[32768 + cur * 16384 + b_base + ((NH)*2 + j) * 1024 + coff[k]]; } }
#define MM(MH, NH) { __builtin_amdgcn_s_setprio(1);                                      \
                     _Pragma("unroll") for (int k = 0; k < 2; ++k) {                     \
                       _Pragma("unroll") for (int i = 0; i < 4; ++i) {                   \
                         _Pragma("unroll") for (int j = 0; j < 2; ++j)                   \
                           acc[(MH)*4 + i][(NH)*2 + j] =                                 \
                             __builtin_amdgcn_mfma_f32_16x16x32_bf16(                    \
                               af[i][k], bfr[j][k], acc[(MH)*4 + i][(NH)*2 + j], 0, 0, 0); } } \
                     __builtin_amdgcn_s_setprio(0); }

    // ---- prologue: stage tile 0 into buf0; leave A13(0) loads in flight ----
    ISS_A(stA, 0, 2, 0);
    ISS_B01(0); ISS_B23(0);
    WRT_A02(0); WRT_B01(0); WRT_B23(0);
    ISS_A(stA, 1, 3, 0);
    asm volatile("s_waitcnt lgkmcnt(0)" ::: "memory");
    __builtin_amdgcn_sched_barrier(0);
    __builtin_amdgcn_s_barrier();

    #pragma unroll 2
    for (int u = 0; u < NT; ++u) {
        const int cur = u & 1;
        const int nxt = cur ^ 1;
        const bool pf = (u + 1 < NT);

        // ---- p0: write A13(u) into buf[cur] (rows 64-128,192-256: read only
        //      at p2); read quadrant frags; issue A02(u+1) ----
        WRT_A13(cur);
        LDA(0); LDB(0);
        if (pf) ISS_A(stA, 0, 2, u + 1);
        __builtin_amdgcn_s_barrier();
        MM(0, 0);
        __builtin_amdgcn_s_barrier();

        // ---- p1 ----
        LDB(1);
        if (pf) ISS_B01(u + 1);
        __builtin_amdgcn_s_barrier();
        MM(0, 1);
        __builtin_amdgcn_s_barrier();

        // ---- p2: write A02(u+1) -> buf[nxt] (tile u-1 regions long dead) ----
        if (pf) WRT_A02(nxt);
        LDA(1); LDB(0);
        if (pf) ISS_B23(u + 1);
        __builtin_amdgcn_s_barrier();
        MM(1, 0);
        __builtin_amdgcn_s_barrier();

        // ---- p3: write B(u+1) -> buf[nxt]; issue A13(u+1) ----
        if (pf) { WRT_B01(nxt); WRT_B23(nxt); }
        LDB(1);
        if (pf) ISS_A(stA, 1, 3, u + 1);
        __builtin_amdgcn_s_barrier();
        MM(1, 1);
        asm volatile("s_waitcnt lgkmcnt(0)" ::: "memory");
        __builtin_amdgcn_sched_barrier(0);
        __builtin_amdgcn_s_barrier();
    }

#undef LDA
#undef LDB
#undef MM

    // ================= fused LSTM epilogue (round-2 verified) =================
    // 1) dump acc (bf16, same numerics as the old gates round-trip) into SM,
    //    transposed [col][row], XOR-swizzled: byte = (col*512+row*2) ^ ((col&7)<<4)
    #pragma unroll
    for (int mi = 0; mi < 8; ++mi) {
        #pragma unroll
        for (int ni = 0; ni < 4; ++ni) {
            int col  = wn * 64 + ni * 16 + l16;          // 0..255 (gate*64 + j)
            int rowb = wm * 128 + mi * 16 + quad * 4;    // 4 consecutive rows
            int addr = (col * 512 + rowb * 2) ^ ((l16 & 7) << 4);
            uint2 pk;
            pk.x = (unsigned)f2bf(acc[mi][ni][0]) | ((unsigned)f2bf(acc[mi][ni][1]) << 16);
            pk.y = (unsigned)f2bf(acc[mi][ni][2]) | ((unsigned)f2bf(acc[mi][ni][3]) << 16);
            *(uint2*)(smB + addr) = pk;
        }
    }
    __syncthreads();

    // 2) each thread: one h-column j = lane, rows wave*32 + [0,32) in 4 chunks of 8
    {
        const int jj = lane;
        const size_t hg = hb0 + jj;                      // global hidden index
        float bs0 = bii[hg] + bhi[hg];
        float bs1 = bif[hg] + bhf[hg];
        float bs2 = big[hg] + bhg[hg];
        float bs3 = bio[hg] + bho[hg];
        const int swz = (jj & 7) << 4;

        #pragma unroll
        for (int c = 0; c < 4; ++c) {
            const int r0 = wave * 32 + c * 8;
            float gi[8], gf[8], gg[8], go[8];
            unpack8(*(const uint4*)(smB + (((0 * 64 + jj) * 512 + r0 * 2) ^ swz)), gi);
            unpack8(*(const uint4*)(smB + (((1 * 64 + jj) * 512 + r0 * 2) ^ swz)), gf);
            unpack8(*(const uint4*)(smB + (((2 * 64 + jj) * 512 + r0 * 2) ^ swz)), gg);
            unpack8(*(const uint4*)(smB + (((3 * 64 + jj) * 512 + r0 * 2) ^ swz)), go);
            #pragma unroll
            for (int e = 0; e < 8; ++e) {
                size_t m = m0 + r0 + e;
                float c0v = c0[m * HID + hg];
                float vi = sigm(gi[e] + bs0);
                float vf = sigm(gf[e] + bs1);
                float vg = tanh_fast(gg[e] + bs2);
                float vo = sigm(go[e] + bs3);
                float cc = vf * c0v + vi * vg;
                out[m * HID + hg]      = vo * tanh_fast(cc);
                out[BH + m * HID + hg] = cc;
            }
        }
    }
}

// ---------- launch ----------
extern "C" void kernel_launch(void* const* d_in, const int* in_sizes, int n_in,
                              void* d_out, int out_size, void* d_ws, size_t ws_size,
                              hipStream_t stream) {
    const float* x   = (const float*)d_in[0];
    const float* h0  = (const float*)d_in[1];
    const float* c0  = (const float*)d_in[2];
    const float* Wii = (const float*)d_in[3];  const float* bii = (const float*)d_in[4];
    const float* Wif = (const float*)d_in[5];  const float* bif = (const float*)d_in[6];
    const float* Wig = (const float*)d_in[7];  const float* big = (const float*)d_in[8];
    const float* Wio = (const float*)d_in[9];  const float* bio = (const float*)d_in[10];
    const float* Whi = (const float*)d_in[11]; const float* bhi = (const float*)d_in[12];
    const float* Whf = (const float*)d_in[13]; const float* bhf = (const float*)d_in[14];
    const float* Whg = (const float*)d_in[15]; const float* bhg = (const float*)d_in[16];
    const float* Who = (const float*)d_in[17]; const float* bho = (const float*)d_in[18];
    float* out = (float*)d_out;

    gemm_lstm_kernel<<<1024, 512, 0, stream>>>(x, h0, c0,
        Wii, Wif, Wig, Wio, Whi, Whf, Whg, Who,
        bii, bhi, bif, bhf, big, bhg, bio, bho, out);
}